// Round 4
// baseline (2593.794 us; speedup 1.0000x reference)
//
#include <hip/hip_runtime.h>

typedef unsigned short u16;

__device__ __forceinline__ float bf2f(u16 v) {
    union { unsigned u; float f; } c; c.u = ((unsigned)v) << 16; return c.f;
}
__device__ __forceinline__ u16 f2bf(float f) {  // RNE f32 -> bf16
    union { float f; unsigned u; } c; c.f = f;
    unsigned r = 0x7FFFu + ((c.u >> 16) & 1u);
    return (u16)((c.u + r) >> 16);
}
__device__ __forceinline__ float4 bf4(ushort4 v) {
    float4 r; r.x = bf2f(v.x); r.y = bf2f(v.y); r.z = bf2f(v.z); r.w = bf2f(v.w); return r;
}

#define B_   4
#define N_   2048
#define INC  256
#define H_   8
#define ROWS 8192

// canonical (bf16) segment offsets within cvt, u16 units
#define SEG_X     0
#define SEG_LN1G  2097152
#define SEG_LN1B  2097408
#define SEG_WQKV  2097664
#define SEG_BQKV  2753024
#define SEG_WM    2755584
#define SEG_BM    3279872
#define SEG_LN2G  3280128
#define SEG_LN2B  3280384
#define SEG_W1    3280640
#define SEG_B1    3542784
#define SEG_W2    3543808
#define SEG_B2    3805952
#define SEG_TOT   3806208

// ---------------- dtype sniffer ----------------
__global__ __launch_bounds__(256) void sniff_k(const u16* __restrict__ x, int* __restrict__ flag) {
    __shared__ int s;
    int t = threadIdx.x;
    if (t == 0) s = 0;
    __syncthreads();
    int bad = 0;
    for (int i = t; i < 8192; i += 256) {
        float v = bf2f(x[i]);
        if (!(fabsf(v) < 1e10f)) bad = 1;   // inf/NaN/huge => fp32 halfwords
    }
    if (bad) atomicOr(&s, 1);
    __syncthreads();
    if (t == 0) *flag = s;   // 1 => inputs fp32, 0 => bf16
}

// ---------------- canonicalize all inputs to bf16 ----------------
__global__ __launch_bounds__(256) void conv_k(
    const void* p0, const void* p1, const void* p2, const void* p3, const void* p4,
    const void* p5, const void* p6, const void* p7, const void* p8, const void* p9,
    const void* p10, const void* p11, const void* p12,
    const int* __restrict__ flag, u16* __restrict__ dst)
{
    int i = blockIdx.x * 256 + threadIdx.x;
    if (i >= SEG_TOT) return;
    const void* p; int j;
    if      (i < SEG_LN1G) { p = p0;  j = i; }
    else if (i < SEG_LN1B) { p = p1;  j = i - SEG_LN1G; }
    else if (i < SEG_WQKV) { p = p2;  j = i - SEG_LN1B; }
    else if (i < SEG_BQKV) { p = p3;  j = i - SEG_WQKV; }
    else if (i < SEG_WM)   { p = p4;  j = i - SEG_BQKV; }
    else if (i < SEG_BM)   { p = p5;  j = i - SEG_WM; }
    else if (i < SEG_LN2G) { p = p6;  j = i - SEG_BM; }
    else if (i < SEG_LN2B) { p = p7;  j = i - SEG_LN2G; }
    else if (i < SEG_W1)   { p = p8;  j = i - SEG_LN2B; }
    else if (i < SEG_B1)   { p = p9;  j = i - SEG_W1; }
    else if (i < SEG_W2)   { p = p10; j = i - SEG_B1; }
    else if (i < SEG_B2)   { p = p11; j = i - SEG_W2; }
    else                   { p = p12; j = i - SEG_B2; }
    dst[i] = (*flag) ? f2bf(((const float*)p)[j]) : ((const u16*)p)[j];
}

// ---------------- LayerNorm over C=256, one block per row, bf16 out ----------------
template<bool BF16IN>
__global__ __launch_bounds__(256) void ln_k(const void* __restrict__ xp,
        const u16* __restrict__ g, const u16* __restrict__ b, u16* __restrict__ y)
{
    int row = blockIdx.x, t = threadIdx.x;
    float v;
    if (BF16IN) v = bf2f(((const u16*)xp)[(size_t)row * INC + t]);
    else        v = ((const float*)xp)[(size_t)row * INC + t];
    float s = v, s2 = v * v;
    #pragma unroll
    for (int o = 32; o > 0; o >>= 1) {
        s  += __shfl_down(s,  o, 64);
        s2 += __shfl_down(s2, o, 64);
    }
    __shared__ float rs[4], rq[4];
    if ((t & 63) == 0) { rs[t >> 6] = s; rq[t >> 6] = s2; }
    __syncthreads();
    float S  = rs[0] + rs[1] + rs[2] + rs[3];
    float S2 = rq[0] + rq[1] + rq[2] + rq[3];
    float mean = S * (1.0f / INC);
    float var  = S2 * (1.0f / INC) - mean * mean;
    float inv  = rsqrtf(var + 1e-5f);
    y[(size_t)row * INC + t] = f2bf((v - mean) * inv * bf2f(g[t]) + bf2f(b[t]));
}

// ---------------- x2 = x + bm (f32), attn merge atomically adds on top ----------------
__global__ __launch_bounds__(256) void initx2_k(const u16* __restrict__ xc,
        const u16* __restrict__ bm, float* __restrict__ x2)
{
    int i = blockIdx.x * 256 + threadIdx.x;
    x2[i] = bf2f(xc[i]) + bf2f(bm[i & 255]);
}

// ---------------- GEMM 64x64 tile, 256 thr, 4x4/thread, BK=16 ----------------
enum { EP_QKV = 0, EP_GELU = 2, EP_FFN2 = 3 };

template<int MODE, bool ABF>
__global__ __launch_bounds__(256) void gemm_k(
    const void* __restrict__ Ap, const u16* __restrict__ Bw,
    const u16* __restrict__ bias, const void* __restrict__ res,
    void* __restrict__ outp,
    u16* __restrict__ qh, u16* __restrict__ kh, u16* __restrict__ vh,
    int N, int K)
{
    __shared__ float As[16][68];
    __shared__ float Bs[16][68];
    const int t  = threadIdx.x;
    const int tx = t & 15, ty = t >> 4;
    const int row0 = blockIdx.y * 64, col0 = blockIdx.x * 64;
    float acc[4][4] = {};

    const int ar = t >> 2, ak = (t & 3) << 2;
    const int bk = t >> 4, bc = (t & 15) << 2;
    const u16* Bptr = Bw + (size_t)bk * N + col0 + bc;

    for (int k0 = 0; k0 < K; k0 += 16) {
        float4 a4;
        if (ABF) {
            ushort4 au = *(const ushort4*)((const u16*)Ap + (size_t)(row0 + ar) * K + ak + k0);
            a4 = bf4(au);
        } else {
            a4 = *(const float4*)((const float*)Ap + (size_t)(row0 + ar) * K + ak + k0);
        }
        ushort4 b4 = *(const ushort4*)(Bptr + (size_t)k0 * N);
        __syncthreads();
        As[ak + 0][ar] = a4.x; As[ak + 1][ar] = a4.y;
        As[ak + 2][ar] = a4.z; As[ak + 3][ar] = a4.w;
        *(float4*)&Bs[bk][bc] = bf4(b4);
        __syncthreads();
        #pragma unroll
        for (int k = 0; k < 16; ++k) {
            float4 av = *(const float4*)&As[k][ty << 2];
            float4 bv = *(const float4*)&Bs[k][tx << 2];
            float a_[4] = {av.x, av.y, av.z, av.w};
            float b_[4] = {bv.x, bv.y, bv.z, bv.w};
            #pragma unroll
            for (int i = 0; i < 4; ++i)
                #pragma unroll
                for (int j = 0; j < 4; ++j)
                    acc[i][j] += a_[i] * b_[j];
        }
    }

    if (MODE == EP_QKV) {
        #pragma unroll
        for (int i = 0; i < 4; ++i) {
            int r = row0 + (ty << 2) + i;
            int bb = r >> 11, n = r & 2047;
            #pragma unroll
            for (int j = 0; j < 4; ++j) {
                int col = col0 + (tx << 2) + j;
                float v = acc[i][j] + bf2f(bias[col]);
                if (col < 256) {
                    qh[(((size_t)(bb * 8 + (col >> 5))) * 2048 + n) * 32 + (col & 31)] = f2bf(v);
                } else if (col < 512) {
                    int c2 = col - 256;
                    kh[(((size_t)(bb * 8 + (c2 >> 5))) * 2048 + n) * 32 + (c2 & 31)] = f2bf(v);
                } else {
                    int cv = col - 512;
                    vh[(((size_t)(bb * 8 + (cv >> 8))) * 2048 + n) * 256 + (cv & 255)] = f2bf(v);
                }
            }
        }
    } else {
        float bz[4];
        #pragma unroll
        for (int j = 0; j < 4; ++j) bz[j] = bf2f(bias[col0 + (tx << 2) + j]);
        #pragma unroll
        for (int i = 0; i < 4; ++i) {
            int r = row0 + (ty << 2) + i;
            size_t base = (size_t)r * N + col0 + (tx << 2);
            float v[4];
            #pragma unroll
            for (int j = 0; j < 4; ++j) v[j] = acc[i][j] + bz[j];
            if (MODE == EP_GELU) {                // exact gelu -> f32 hidden
                #pragma unroll
                for (int j = 0; j < 4; ++j)
                    v[j] = 0.5f * v[j] * (1.0f + erff(v[j] * 0.70710678118654752f));
                float4 o = {v[0], v[1], v[2], v[3]};
                *(float4*)((float*)outp + base) = o;
            } else {                              // EP_FFN2: + residual x2 (f32) -> FP32 out
                const float* R = (const float*)res;
                #pragma unroll
                for (int j = 0; j < 4; ++j) v[j] += R[base + j];
                float4 o = {v[0], v[1], v[2], v[3]};
                *(float4*)((float*)outp + base) = o;   // d_out is float32 (reference output dtype)
            }
        }
    }
}

// ---------------- Flash attention + fused merge projection ----------------
// grid (N/32, H, B), 256 threads. Q-tile 32 rows; K-tiles of 64; V dim 256.
// Epilogue: O_tile[32,256] @ Wm[h*256:(h+1)*256, 0:256] atomically added to x2.
__global__ __launch_bounds__(256) void attn_merge_k(
    const u16* __restrict__ qh, const u16* __restrict__ kh,
    const u16* __restrict__ vh, const u16* __restrict__ Wm,
    float* __restrict__ x2)
{
    const int t = threadIdx.x;
    const int qt = blockIdx.x, h = blockIdx.y, b = blockIdx.z;
    const int n0 = qt * 32;
    const float scale = 0.17677669529663687f;  // 1/sqrt(32)
    const u16* Q  = qh + ((size_t)(b * 8 + h)) * 2048 * 32;
    const u16* Kp = kh + ((size_t)(b * 8 + h)) * 2048 * 32;
    const u16* V  = vh + ((size_t)(b * 8 + h)) * 2048 * 256;

    __shared__ float Qs[32][36];
    __shared__ float Ks[64][36];
    __shared__ float S[32][65];
    __shared__ float Os[32][257];
    __shared__ float mrow[32], lrow[32], arow[32];

    {
        int r = t >> 3, c = (t & 7) << 2;
        ushort4 q4 = *(const ushort4*)(Q + (size_t)(n0 + r) * 32 + c);
        *(float4*)&Qs[r][c] = bf4(q4);
    }
    if (t < 32) { mrow[t] = -1e30f; lrow[t] = 0.0f; }

    float o[8][4] = {};
    const int cg = (t & 63) << 2;
    const int qb = t >> 6;

    for (int kt = 0; kt < 2048; kt += 64) {
        __syncthreads();
        {
            int r = t >> 3, c = (t & 7) << 2;
            ushort4 k0 = *(const ushort4*)(Kp + (size_t)(kt + r) * 32 + c);
            ushort4 k1 = *(const ushort4*)(Kp + (size_t)(kt + r + 32) * 32 + c);
            *(float4*)&Ks[r][c]      = bf4(k0);
            *(float4*)&Ks[r + 32][c] = bf4(k1);
        }
        __syncthreads();
        {
            int q = t & 31, jg = t >> 5;
            #pragma unroll
            for (int jj = 0; jj < 8; ++jj) {
                int j = jg * 8 + jj;
                float s = 0.0f;
                #pragma unroll
                for (int c = 0; c < 32; c += 4) {
                    float4 qv = *(const float4*)&Qs[q][c];
                    float4 kv = *(const float4*)&Ks[j][c];
                    s += qv.x * kv.x + qv.y * kv.y + qv.z * kv.z + qv.w * kv.w;
                }
                S[q][j] = s * scale;
            }
        }
        __syncthreads();
        if (t < 32) {
            float m_old = mrow[t], m = m_old;
            #pragma unroll 8
            for (int j = 0; j < 64; ++j) m = fmaxf(m, S[t][j]);
            float sum = 0.0f;
            #pragma unroll 8
            for (int j = 0; j < 64; ++j) {
                float p = __expf(S[t][j] - m);
                S[t][j] = p; sum += p;
            }
            float al = __expf(m_old - m);
            lrow[t] = lrow[t] * al + sum;
            mrow[t] = m; arow[t] = al;
        }
        __syncthreads();
        #pragma unroll
        for (int i = 0; i < 8; ++i) {
            float al = arow[qb + 4 * i];
            o[i][0] *= al; o[i][1] *= al; o[i][2] *= al; o[i][3] *= al;
        }
        for (int j = 0; j < 64; ++j) {
            ushort4 vu = *(const ushort4*)(V + (size_t)(kt + j) * 256 + cg);
            float4 v4 = bf4(vu);
            #pragma unroll
            for (int i = 0; i < 8; ++i) {
                float p = S[qb + 4 * i][j];
                o[i][0] += p * v4.x; o[i][1] += p * v4.y;
                o[i][2] += p * v4.z; o[i][3] += p * v4.w;
            }
        }
    }
    __syncthreads();
    // normalize into LDS: Os[q][vchan]
    #pragma unroll
    for (int i = 0; i < 8; ++i) {
        int q = qb + 4 * i;
        float rl = 1.0f / lrow[q];
        Os[q][cg + 0] = o[i][0] * rl; Os[q][cg + 1] = o[i][1] * rl;
        Os[q][cg + 2] = o[i][2] * rl; Os[q][cg + 3] = o[i][3] * rl;
    }
    __syncthreads();
    // merge: contrib[q][c] = sum_k Os[q][k] * Wm[h*256+k][c]
    float m_[8][4] = {};
    const u16* Wh = Wm + (size_t)h * 256 * 256;
    for (int k = 0; k < 256; ++k) {
        float4 w4 = bf4(*(const ushort4*)(Wh + (size_t)k * 256 + cg));
        #pragma unroll
        for (int i = 0; i < 8; ++i) {
            float os = Os[qb + 4 * i][k];   // wave-uniform broadcast
            m_[i][0] += os * w4.x; m_[i][1] += os * w4.y;
            m_[i][2] += os * w4.z; m_[i][3] += os * w4.w;
        }
    }
    #pragma unroll
    for (int i = 0; i < 8; ++i) {
        int q = qb + 4 * i;
        float* dst = x2 + ((size_t)(b * 2048 + n0 + q)) * 256 + cg;
        atomicAdd(dst + 0, m_[i][0]); atomicAdd(dst + 1, m_[i][1]);
        atomicAdd(dst + 2, m_[i][2]); atomicAdd(dst + 3, m_[i][3]);
    }
}

extern "C" void kernel_launch(void* const* d_in, const int* in_sizes, int n_in,
                              void* d_out, int out_size, void* d_ws, size_t ws_size,
                              hipStream_t stream)
{
    u16* wsu = (u16*)d_ws;
    int* flag = (int*)d_ws;

    // workspace layout (u16 units), total 62,138,624 bytes (~59.3 MB)
    const size_t CVT0 = 64;
    const size_t Y0   = 3806336;                 // bf16 [8192,256]
    const size_t QH0  = Y0  + 2097152;           //  5,903,488
    const size_t KH0  = QH0 + 2097152;           //  8,000,640
    const size_t VH0  = KH0 + 2097152;           // 10,097,792
    const size_t X20  = VH0 + 16777216;          // 26,875,008 (f32 [8192,256])
    // hb f32 [8192,1024] aliases qh/kh/vh (dead after attention)

    u16* cvt = wsu + CVT0;
    u16* y   = wsu + Y0;
    u16* qh  = wsu + QH0;
    u16* kh  = wsu + KH0;
    u16* vh  = wsu + VH0;
    float* x2 = (float*)(wsu + X20);
    float* hb = (float*)(wsu + QH0);

    const u16* xc   = cvt + SEG_X;
    const u16* ln1g = cvt + SEG_LN1G;
    const u16* ln1b = cvt + SEG_LN1B;
    const u16* Wqkv = cvt + SEG_WQKV;
    const u16* bqkv = cvt + SEG_BQKV;
    const u16* Wm   = cvt + SEG_WM;
    const u16* bm   = cvt + SEG_BM;
    const u16* ln2g = cvt + SEG_LN2G;
    const u16* ln2b = cvt + SEG_LN2B;
    const u16* W1   = cvt + SEG_W1;
    const u16* b1   = cvt + SEG_B1;
    const u16* W2   = cvt + SEG_W2;
    const u16* b2   = cvt + SEG_B2;

    sniff_k<<<1, 256, 0, stream>>>((const u16*)d_in[0], flag);
    conv_k<<<SEG_TOT / 256, 256, 0, stream>>>(
        d_in[0], d_in[1], d_in[2], d_in[3], d_in[4], d_in[5], d_in[6],
        d_in[7], d_in[8], d_in[9], d_in[10], d_in[11], d_in[12], flag, cvt);

    ln_k<true><<<ROWS, 256, 0, stream>>>(xc, ln1g, ln1b, y);
    gemm_k<EP_QKV, true><<<dim3(2560 / 64, ROWS / 64), 256, 0, stream>>>(
        y, Wqkv, bqkv, nullptr, nullptr, qh, kh, vh, 2560, 256);
    initx2_k<<<ROWS, 256, 0, stream>>>(xc, bm, x2);
    attn_merge_k<<<dim3(N_ / 32, H_, B_), 256, 0, stream>>>(qh, kh, vh, Wm, x2);
    ln_k<false><<<ROWS, 256, 0, stream>>>(x2, ln2g, ln2b, y);
    gemm_k<EP_GELU, true><<<dim3(1024 / 64, ROWS / 64), 256, 0, stream>>>(
        y, W1, b1, nullptr, hb, nullptr, nullptr, nullptr, 1024, 256);
    gemm_k<EP_FFN2, false><<<dim3(256 / 64, ROWS / 64), 256, 0, stream>>>(
        hb, W2, b2, x2, d_out, nullptr, nullptr, nullptr, 256, 1024);
}

// Round 6
// 707.605 us; speedup vs baseline: 3.6656x; 3.6656x over previous
//
#include <hip/hip_runtime.h>

typedef unsigned short u16;
typedef __attribute__((ext_vector_type(8))) short bf8_t;   // 8 bf16 (4 VGPR) MFMA A/B frag
typedef __attribute__((ext_vector_type(4))) float f4_t;    // MFMA C/D frag

__device__ __forceinline__ float bf2f(u16 v) {
    union { unsigned u; float f; } c; c.u = ((unsigned)v) << 16; return c.f;
}
__device__ __forceinline__ u16 f2bf(float f) {  // RNE f32 -> bf16
    union { float f; unsigned u; } c; c.f = f;
    unsigned r = 0x7FFFu + ((c.u >> 16) & 1u);
    return (u16)((c.u + r) >> 16);
}
__device__ __forceinline__ float4 bf4(ushort4 v) {
    float4 r; r.x = bf2f(v.x); r.y = bf2f(v.y); r.z = bf2f(v.z); r.w = bf2f(v.w); return r;
}

#define B_   4
#define N_   2048
#define INC  256
#define H_   8
#define ROWS 8192

// canonical (bf16) segment offsets within cvt, u16 units
#define SEG_X     0
#define SEG_LN1G  2097152
#define SEG_LN1B  2097408
#define SEG_WQKV  2097664
#define SEG_BQKV  2753024
#define SEG_WM    2755584
#define SEG_BM    3279872
#define SEG_LN2G  3280128
#define SEG_LN2B  3280384
#define SEG_W1    3280640
#define SEG_B1    3542784
#define SEG_W2    3543808
#define SEG_B2    3805952
#define SEG_TOT   3806208

// ---------------- dtype sniffer ----------------
__global__ __launch_bounds__(256) void sniff_k(const u16* __restrict__ x, int* __restrict__ flag) {
    __shared__ int s;
    int t = threadIdx.x;
    if (t == 0) s = 0;
    __syncthreads();
    int bad = 0;
    for (int i = t; i < 8192; i += 256) {
        float v = bf2f(x[i]);
        if (!(fabsf(v) < 1e10f)) bad = 1;
    }
    if (bad) atomicOr(&s, 1);
    __syncthreads();
    if (t == 0) *flag = s;   // 1 => inputs fp32, 0 => bf16
}

// ---------------- canonicalize all inputs to bf16 ----------------
__global__ __launch_bounds__(256) void conv_k(
    const void* p0, const void* p1, const void* p2, const void* p3, const void* p4,
    const void* p5, const void* p6, const void* p7, const void* p8, const void* p9,
    const void* p10, const void* p11, const void* p12,
    const int* __restrict__ flag, u16* __restrict__ dst)
{
    int i = blockIdx.x * 256 + threadIdx.x;
    if (i >= SEG_TOT) return;
    const void* p; int j;
    if      (i < SEG_LN1G) { p = p0;  j = i; }
    else if (i < SEG_LN1B) { p = p1;  j = i - SEG_LN1G; }
    else if (i < SEG_WQKV) { p = p2;  j = i - SEG_LN1B; }
    else if (i < SEG_BQKV) { p = p3;  j = i - SEG_WQKV; }
    else if (i < SEG_WM)   { p = p4;  j = i - SEG_BQKV; }
    else if (i < SEG_BM)   { p = p5;  j = i - SEG_WM; }
    else if (i < SEG_LN2G) { p = p6;  j = i - SEG_BM; }
    else if (i < SEG_LN2B) { p = p7;  j = i - SEG_LN2G; }
    else if (i < SEG_W1)   { p = p8;  j = i - SEG_LN2B; }
    else if (i < SEG_B1)   { p = p9;  j = i - SEG_W1; }
    else if (i < SEG_W2)   { p = p10; j = i - SEG_B1; }
    else if (i < SEG_B2)   { p = p11; j = i - SEG_W2; }
    else                   { p = p12; j = i - SEG_B2; }
    dst[i] = (*flag) ? f2bf(((const float*)p)[j]) : ((const u16*)p)[j];
}

// ---------------- LayerNorm over C=256, one block per row, bf16 out ----------------
template<bool BF16IN>
__global__ __launch_bounds__(256) void ln_k(const void* __restrict__ xp,
        const u16* __restrict__ g, const u16* __restrict__ b, u16* __restrict__ y)
{
    int row = blockIdx.x, t = threadIdx.x;
    float v;
    if (BF16IN) v = bf2f(((const u16*)xp)[(size_t)row * INC + t]);
    else        v = ((const float*)xp)[(size_t)row * INC + t];
    float s = v, s2 = v * v;
    #pragma unroll
    for (int o = 32; o > 0; o >>= 1) {
        s  += __shfl_down(s,  o, 64);
        s2 += __shfl_down(s2, o, 64);
    }
    __shared__ float rs[4], rq[4];
    if ((t & 63) == 0) { rs[t >> 6] = s; rq[t >> 6] = s2; }
    __syncthreads();
    float S  = rs[0] + rs[1] + rs[2] + rs[3];
    float S2 = rq[0] + rq[1] + rq[2] + rq[3];
    float mean = S * (1.0f / INC);
    float var  = S2 * (1.0f / INC) - mean * mean;
    float inv  = rsqrtf(var + 1e-5f);
    y[(size_t)row * INC + t] = f2bf((v - mean) * inv * bf2f(g[t]) + bf2f(b[t]));
}

// ---------------- GEMM 64x64 tile, 256 thr, 4x4/thread, BK=16 ----------------
enum { EP_QKV = 0, EP_MERGE = 1, EP_GELU = 2, EP_FFN2 = 3 };

template<int MODE, bool ABF>
__global__ __launch_bounds__(256) void gemm_k(
    const void* __restrict__ Ap, const u16* __restrict__ Bw,
    const u16* __restrict__ bias, const void* __restrict__ res,
    void* __restrict__ outp,
    u16* __restrict__ qh, u16* __restrict__ kh, u16* __restrict__ vh,
    int N, int K)
{
    __shared__ float As[16][68];
    __shared__ float Bs[16][68];
    const int t  = threadIdx.x;
    const int tx = t & 15, ty = t >> 4;
    const int row0 = blockIdx.y * 64, col0 = blockIdx.x * 64;
    float acc[4][4] = {};

    const int ar = t >> 2, ak = (t & 3) << 2;
    const int bk = t >> 4, bc = (t & 15) << 2;
    const u16* Bptr = Bw + (size_t)bk * N + col0 + bc;

    for (int k0 = 0; k0 < K; k0 += 16) {
        float4 a4;
        if (ABF) {
            ushort4 au = *(const ushort4*)((const u16*)Ap + (size_t)(row0 + ar) * K + ak + k0);
            a4 = bf4(au);
        } else {
            a4 = *(const float4*)((const float*)Ap + (size_t)(row0 + ar) * K + ak + k0);
        }
        ushort4 b4 = *(const ushort4*)(Bptr + (size_t)k0 * N);
        __syncthreads();
        As[ak + 0][ar] = a4.x; As[ak + 1][ar] = a4.y;
        As[ak + 2][ar] = a4.z; As[ak + 3][ar] = a4.w;
        *(float4*)&Bs[bk][bc] = bf4(b4);
        __syncthreads();
        #pragma unroll
        for (int k = 0; k < 16; ++k) {
            float4 av = *(const float4*)&As[k][ty << 2];
            float4 bv = *(const float4*)&Bs[k][tx << 2];
            float a_[4] = {av.x, av.y, av.z, av.w};
            float b_[4] = {bv.x, bv.y, bv.z, bv.w};
            #pragma unroll
            for (int i = 0; i < 4; ++i)
                #pragma unroll
                for (int j = 0; j < 4; ++j)
                    acc[i][j] += a_[i] * b_[j];
        }
    }

    if (MODE == EP_QKV) {
        if (col0 >= 512) {
            // V region: transpose tile through LDS, write vhT[vchan][n] coalesced
            __shared__ u16 Ts[64][72];   // Ts[channel][token]
            __syncthreads();             // all As/Bs reads done (Ts may alias)
            #pragma unroll
            for (int i = 0; i < 4; ++i)
                #pragma unroll
                for (int j = 0; j < 4; ++j)
                    Ts[(tx << 2) + j][(ty << 2) + i] =
                        f2bf(acc[i][j] + bf2f(bias[col0 + (tx << 2) + j]));
            __syncthreads();
            int vcg = col0 - 512;
            int hh  = vcg >> 8;
            int bb  = row0 >> 11, nb = row0 & 2047;
            int cl  = t >> 2, seg = t & 3;
            size_t dstrow = (size_t)(bb * 8 + hh) * 256 + (vcg & 255) + cl;
            u16* dp = vh + dstrow * 2048 + nb + seg * 16;
            #pragma unroll
            for (int ii = 0; ii < 16; ii += 4)
                *(ushort4*)(dp + ii) = *(const ushort4*)&Ts[cl][seg * 16 + ii];
        } else {
            #pragma unroll
            for (int i = 0; i < 4; ++i) {
                int r = row0 + (ty << 2) + i;
                int bb = r >> 11, n = r & 2047;
                #pragma unroll
                for (int j = 0; j < 4; ++j) {
                    int col = col0 + (tx << 2) + j;
                    float v = acc[i][j] + bf2f(bias[col]);
                    if (col < 256) {
                        qh[(((size_t)(bb * 8 + (col >> 5))) * 2048 + n) * 32 + (col & 31)] = f2bf(v);
                    } else {
                        int c2 = col - 256;
                        kh[(((size_t)(bb * 8 + (c2 >> 5))) * 2048 + n) * 32 + (c2 & 31)] = f2bf(v);
                    }
                }
            }
        }
    } else {
        float bz[4];
        #pragma unroll
        for (int j = 0; j < 4; ++j) bz[j] = bf2f(bias[col0 + (tx << 2) + j]);
        #pragma unroll
        for (int i = 0; i < 4; ++i) {
            int r = row0 + (ty << 2) + i;
            size_t base = (size_t)r * N + col0 + (tx << 2);
            float v[4];
            #pragma unroll
            for (int j = 0; j < 4; ++j) v[j] = acc[i][j] + bz[j];
            if (MODE == EP_MERGE) {               // + residual x (bf16) -> f32 x2
                const u16* R = (const u16*)res;
                #pragma unroll
                for (int j = 0; j < 4; ++j) v[j] += bf2f(R[base + j]);
                float4 o = {v[0], v[1], v[2], v[3]};
                *(float4*)((float*)outp + base) = o;
            } else if (MODE == EP_GELU) {          // exact gelu -> f32 hidden
                #pragma unroll
                for (int j = 0; j < 4; ++j)
                    v[j] = 0.5f * v[j] * (1.0f + erff(v[j] * 0.70710678118654752f));
                float4 o = {v[0], v[1], v[2], v[3]};
                *(float4*)((float*)outp + base) = o;
            } else {                               // EP_FFN2: + residual x2 (f32) -> fp32 d_out
                const float* R = (const float*)res;
                #pragma unroll
                for (int j = 0; j < 4; ++j) v[j] += R[base + j];
                float4 o = {v[0], v[1], v[2], v[3]};
                *(float4*)((float*)outp + base) = o;
            }
        }
    }
}

// ---------------- MFMA flash attention ----------------
// grid (32, H, B), 256 thr = 4 waves. Block: 64 q rows. Wave w: softmax rows
// 16w..16w+15, O columns 64w..64w+63. K-tile = 64 keys.
// K,V fragments direct from global (V pre-transposed vhT[vc][key]); P via LDS.
__global__ __launch_bounds__(256) void attn_k(
    const u16* __restrict__ qh, const u16* __restrict__ kh,
    const u16* __restrict__ vhT, u16* __restrict__ ao)
{
    const int t = threadIdx.x;
    const int w = t >> 6, lane = t & 63;
    const int l15 = lane & 15, quad = lane >> 4;
    const int qt = blockIdx.x, h = blockIdx.y, b = blockIdx.z;
    const int n0 = qt * 64;
    const float scale = 0.17677669529663687f;  // 1/sqrt(32)
    const size_t bh = (size_t)(b * 8 + h);
    const u16* Q  = qh  + bh * 2048 * 32;
    const u16* Kp = kh  + bh * 2048 * 32;
    const u16* Vt = vhT + bh * 256 * 2048;     // [vchan][key]

    __shared__ __align__(16) u16 Pb[64][72];
    __shared__ __align__(16) float alf[64];
    __shared__ __align__(16) float lds_l[64];
    __shared__ int flags[4];

    // Q fragment (A): lane holds Q[n0+16w+l15][quad*8 .. +7], held all kernel
    const bf8_t qf = *(const bf8_t*)(Q + (size_t)(n0 + 16 * w + l15) * 32 + quad * 8);

    f4_t acc[4][4];
    #pragma unroll
    for (int i = 0; i < 4; ++i)
        #pragma unroll
        for (int j = 0; j < 4; ++j)
            acc[i][j] = (f4_t){0.f, 0.f, 0.f, 0.f};
    float m4[4] = {-1e30f, -1e30f, -1e30f, -1e30f};
    float l4[4] = {0.f, 0.f, 0.f, 0.f};
    const f4_t zf = {0.f, 0.f, 0.f, 0.f};

    for (int kt = 0; kt < 2048; kt += 64) {
        // ---- S = Q K^T for this wave's 16 rows x 64 keys (4 MFMAs, K=32) ----
        f4_t s[4];
        #pragma unroll
        for (int jt = 0; jt < 4; ++jt) {
            bf8_t kf = *(const bf8_t*)(Kp + (size_t)(kt + jt * 16 + l15) * 32 + quad * 8);
            s[jt] = __builtin_amdgcn_mfma_f32_16x16x32_bf16(qf, kf, zf, 0, 0, 0);
        }
        // ---- online softmax (rows = quad*4+r), P -> LDS bf16 ----
        float al[4];
        int any = 0;
        #pragma unroll
        for (int r = 0; r < 4; ++r) {
            float v0 = s[0][r] * scale, v1 = s[1][r] * scale;
            float v2 = s[2][r] * scale, v3 = s[3][r] * scale;
            float tm = fmaxf(fmaxf(v0, v1), fmaxf(v2, v3));
            #pragma unroll
            for (int d = 1; d < 16; d <<= 1) tm = fmaxf(tm, __shfl_xor(tm, d, 64));
            float mo = m4[r], mn = fmaxf(mo, tm);
            float a = __expf(mo - mn);
            float p0 = __expf(v0 - mn), p1 = __expf(v1 - mn);
            float p2 = __expf(v2 - mn), p3 = __expf(v3 - mn);
            float rsum = p0 + p1 + p2 + p3;
            #pragma unroll
            for (int d = 1; d < 16; d <<= 1) rsum += __shfl_xor(rsum, d, 64);
            m4[r] = mn; l4[r] = l4[r] * a + rsum; al[r] = a;
            any |= (a < 1.0f);
            int row = 16 * w + quad * 4 + r;
            Pb[row][l15]      = f2bf(p0);
            Pb[row][16 + l15] = f2bf(p1);
            Pb[row][32 + l15] = f2bf(p2);
            Pb[row][48 + l15] = f2bf(p3);
        }
        if (l15 == 0) {
            #pragma unroll
            for (int r = 0; r < 4; ++r) alf[16 * w + quad * 4 + r] = al[r];
        }
        unsigned long long bal = __ballot(any);
        if (lane == 0) flags[w] = (bal != 0ULL);
        __syncthreads();
        // ---- rescale O by alpha (all 64 rows), skipped when no row changed max ----
        if (flags[0] | flags[1] | flags[2] | flags[3]) {
            #pragma unroll
            for (int mt = 0; mt < 4; ++mt) {
                f4_t a4 = *(const f4_t*)&alf[mt * 16 + quad * 4];
                #pragma unroll
                for (int nt = 0; nt < 4; ++nt)
                    #pragma unroll
                    for (int r = 0; r < 4; ++r)
                        acc[mt][nt][r] *= a4[r];
            }
        }
        // ---- O += P V : A = P from LDS, B = V direct global (vhT) ----
        #pragma unroll
        for (int kc = 0; kc < 2; ++kc) {
            bf8_t af[4];
            #pragma unroll
            for (int mt = 0; mt < 4; ++mt)
                af[mt] = *(const bf8_t*)&Pb[mt * 16 + l15][kc * 32 + quad * 8];
            #pragma unroll
            for (int nt = 0; nt < 4; ++nt) {
                bf8_t vf = *(const bf8_t*)(Vt + (size_t)(64 * w + nt * 16 + l15) * 2048
                                           + kt + kc * 32 + quad * 8);
                #pragma unroll
                for (int mt = 0; mt < 4; ++mt)
                    acc[mt][nt] = __builtin_amdgcn_mfma_f32_16x16x32_bf16(
                        af[mt], vf, acc[mt][nt], 0, 0, 0);
            }
        }
        __syncthreads();   // protect Pb/alf/flags for next iteration
    }

    // ---- epilogue: O /= l, write ao[b, n, h*256 + vc] bf16 ----
    if (l15 == 0) {
        #pragma unroll
        for (int r = 0; r < 4; ++r) lds_l[16 * w + quad * 4 + r] = l4[r];
    }
    __syncthreads();
    #pragma unroll
    for (int mt = 0; mt < 4; ++mt) {
        f4_t lv = *(const f4_t*)&lds_l[mt * 16 + quad * 4];
        #pragma unroll
        for (int r = 0; r < 4; ++r) {
            float inv = 1.0f / lv[r];
            size_t rowbase = ((size_t)(b * 2048 + n0 + mt * 16 + quad * 4 + r)) * 2048
                             + h * 256 + 64 * w;
            #pragma unroll
            for (int nt = 0; nt < 4; ++nt)
                ao[rowbase + nt * 16 + l15] = f2bf(acc[mt][nt][r] * inv);
        }
    }
}

extern "C" void kernel_launch(void* const* d_in, const int* in_sizes, int n_in,
                              void* d_out, int out_size, void* d_ws, size_t ws_size,
                              hipStream_t stream)
{
    u16* wsu = (u16*)d_ws;
    int* flag = (int*)d_ws;

    // workspace layout (u16 units), total ~95.7 MB
    const size_t CVT0 = 64;
    const size_t Y0   = 3806272;                 // bf16 [8192,256]
    const size_t QH0  = Y0  + 2097152;           //  5,903,424
    const size_t KH0  = QH0 + 2097152;           //  8,000,576
    const size_t VT0  = KH0 + 2097152;           // 10,097,728  vhT bf16 [B*H*256][2048]
    const size_t AO0  = VT0 + 16777216;          // 26,874,944  ao bf16 [8192][2048]
    const size_t X20  = AO0 + 16777216;          // 43,652,160  x2 f32 [8192,256]
    // hb f32 [8192,1024] aliases ao (dead after merge GEMM)

    u16* cvt = wsu + CVT0;
    u16* y   = wsu + Y0;
    u16* qh  = wsu + QH0;
    u16* kh  = wsu + KH0;
    u16* vhT = wsu + VT0;
    u16* ao  = wsu + AO0;
    float* x2 = (float*)(wsu + X20);
    float* hb = (float*)(wsu + AO0);

    const u16* xc   = cvt + SEG_X;
    const u16* ln1g = cvt + SEG_LN1G;
    const u16* ln1b = cvt + SEG_LN1B;
    const u16* Wqkv = cvt + SEG_WQKV;
    const u16* bqkv = cvt + SEG_BQKV;
    const u16* Wm   = cvt + SEG_WM;
    const u16* bm   = cvt + SEG_BM;
    const u16* ln2g = cvt + SEG_LN2G;
    const u16* ln2b = cvt + SEG_LN2B;
    const u16* W1   = cvt + SEG_W1;
    const u16* b1   = cvt + SEG_B1;
    const u16* W2   = cvt + SEG_W2;
    const u16* b2   = cvt + SEG_B2;

    sniff_k<<<1, 256, 0, stream>>>((const u16*)d_in[0], flag);
    conv_k<<<SEG_TOT / 256, 256, 0, stream>>>(
        d_in[0], d_in[1], d_in[2], d_in[3], d_in[4], d_in[5], d_in[6],
        d_in[7], d_in[8], d_in[9], d_in[10], d_in[11], d_in[12], flag, cvt);

    ln_k<true><<<ROWS, 256, 0, stream>>>(xc, ln1g, ln1b, y);
    gemm_k<EP_QKV, true><<<dim3(2560 / 64, ROWS / 64), 256, 0, stream>>>(
        y, Wqkv, bqkv, nullptr, nullptr, qh, kh, vhT, 2560, 256);
    attn_k<<<dim3(32, H_, B_), 256, 0, stream>>>(qh, kh, vhT, ao);
    gemm_k<EP_MERGE, true><<<dim3(256 / 64, ROWS / 64), 256, 0, stream>>>(
        ao, Wm, bm, xc, x2, nullptr, nullptr, nullptr, 256, 2048);
    ln_k<false><<<ROWS, 256, 0, stream>>>(x2, ln2g, ln2b, y);
    gemm_k<EP_GELU, true><<<dim3(1024 / 64, ROWS / 64), 256, 0, stream>>>(
        y, W1, b1, nullptr, hb, nullptr, nullptr, nullptr, 1024, 256);
    gemm_k<EP_FFN2, false><<<dim3(256 / 64, ROWS / 64), 256, 0, stream>>>(
        hb, W2, b2, x2, d_out, nullptr, nullptr, nullptr, 256, 1024);
}

// Round 7
// 501.562 us; speedup vs baseline: 5.1714x; 1.4108x over previous
//
#include <hip/hip_runtime.h>

typedef unsigned short u16;
typedef __attribute__((ext_vector_type(8))) short bf8_t;   // 8 bf16 (4 VGPR) MFMA A/B frag
typedef __attribute__((ext_vector_type(4))) float f4_t;    // MFMA C/D frag

__device__ __forceinline__ float bf2f(u16 v) {
    union { unsigned u; float f; } c; c.u = ((unsigned)v) << 16; return c.f;
}
__device__ __forceinline__ u16 f2bf(float f) {  // RNE f32 -> bf16
    union { float f; unsigned u; } c; c.f = f;
    unsigned r = 0x7FFFu + ((c.u >> 16) & 1u);
    return (u16)((c.u + r) >> 16);
}

#define B_   4
#define N_   2048
#define INC  256
#define H_   8
#define ROWS 8192

// canonical (bf16) segment offsets within cvt, u16 units. Weights stored TRANSPOSED: Bt[n][k].
#define SEG_X     0
#define SEG_LN1G  2097152
#define SEG_LN1B  2097408
#define SEG_WQKV  2097664
#define SEG_BQKV  2753024
#define SEG_WM    2755584
#define SEG_BM    3279872
#define SEG_LN2G  3280128
#define SEG_LN2B  3280384
#define SEG_W1    3280640
#define SEG_B1    3542784
#define SEG_W2    3543808
#define SEG_B2    3805952
#define SEG_TOT   3806208

// ---------------- dtype sniffer ----------------
__global__ __launch_bounds__(256) void sniff_k(const u16* __restrict__ x, int* __restrict__ flag) {
    __shared__ int s;
    int t = threadIdx.x;
    if (t == 0) s = 0;
    __syncthreads();
    int bad = 0;
    for (int i = t; i < 8192; i += 256) {
        float v = bf2f(x[i]);
        if (!(fabsf(v) < 1e10f)) bad = 1;
    }
    if (bad) atomicOr(&s, 1);
    __syncthreads();
    if (t == 0) *flag = s;   // 1 => inputs fp32, 0 => bf16
}

// ---------------- canonicalize inputs to bf16; weights transposed ----------------
__global__ __launch_bounds__(256) void conv_k(
    const void* p0, const void* p1, const void* p2, const void* p3, const void* p4,
    const void* p5, const void* p6, const void* p7, const void* p8, const void* p9,
    const void* p10, const void* p11, const void* p12,
    const int* __restrict__ flag, u16* __restrict__ dst)
{
    int i = blockIdx.x * 256 + threadIdx.x;
    if (i >= SEG_TOT) return;
    const void* p; int j;
    if      (i < SEG_LN1G) { p = p0;  j = i; }
    else if (i < SEG_LN1B) { p = p1;  j = i - SEG_LN1G; }
    else if (i < SEG_WQKV) { p = p2;  j = i - SEG_LN1B; }
    else if (i < SEG_BQKV) { p = p3;  int ii = i - SEG_WQKV;          // WqkvT[n][k]: n<2560,k<256
                             int n = ii >> 8, k = ii & 255; j = k * 2560 + n; }
    else if (i < SEG_WM)   { p = p4;  j = i - SEG_BQKV; }
    else if (i < SEG_BM)   { p = p5;  int ii = i - SEG_WM;            // WmT[n][k]: n<256,k<2048
                             int n = ii >> 11, k = ii & 2047; j = k * 256 + n; }
    else if (i < SEG_LN2G) { p = p6;  j = i - SEG_BM; }
    else if (i < SEG_LN2B) { p = p7;  j = i - SEG_LN2G; }
    else if (i < SEG_W1)   { p = p8;  j = i - SEG_LN2B; }
    else if (i < SEG_B1)   { p = p9;  int ii = i - SEG_W1;            // W1T[n][k]: n<1024,k<256
                             int n = ii >> 8, k = ii & 255; j = k * 1024 + n; }
    else if (i < SEG_W2)   { p = p10; j = i - SEG_B1; }
    else if (i < SEG_B2)   { p = p11; int ii = i - SEG_W2;            // W2T[n][k]: n<256,k<1024
                             int n = ii >> 10, k = ii & 1023; j = k * 256 + n; }
    else                   { p = p12; j = i - SEG_B2; }
    dst[i] = (*flag) ? f2bf(((const float*)p)[j]) : ((const u16*)p)[j];
}

// ---------------- LayerNorm over C=256, one block per row, bf16 out ----------------
template<bool BF16IN>
__global__ __launch_bounds__(256) void ln_k(const void* __restrict__ xp,
        const u16* __restrict__ g, const u16* __restrict__ b, u16* __restrict__ y)
{
    int row = blockIdx.x, t = threadIdx.x;
    float v;
    if (BF16IN) v = bf2f(((const u16*)xp)[(size_t)row * INC + t]);
    else        v = ((const float*)xp)[(size_t)row * INC + t];
    float s = v, s2 = v * v;
    #pragma unroll
    for (int o = 32; o > 0; o >>= 1) {
        s  += __shfl_down(s,  o, 64);
        s2 += __shfl_down(s2, o, 64);
    }
    __shared__ float rs[4], rq[4];
    if ((t & 63) == 0) { rs[t >> 6] = s; rq[t >> 6] = s2; }
    __syncthreads();
    float S  = rs[0] + rs[1] + rs[2] + rs[3];
    float S2 = rq[0] + rq[1] + rq[2] + rq[3];
    float mean = S * (1.0f / INC);
    float var  = S2 * (1.0f / INC) - mean * mean;
    float inv  = rsqrtf(var + 1e-5f);
    y[(size_t)row * INC + t] = f2bf((v - mean) * inv * bf2f(g[t]) + bf2f(b[t]));
}

// ---------------- MFMA GEMM: C[M,N] = A[M,K](bf16) @ Bt[N,K]^T + epilogue ----------------
// Block 256 thr = 4 waves; tile M=128 (wave w: rows 32w..32w+31), N=64.
// A,B fragments loaded DIRECTLY from global (both k-contiguous); no LDS mainloop.
enum { EP_QKV = 0, EP_MERGE = 1, EP_GELU = 2, EP_FFN2 = 3 };

template<int MODE>
__global__ __launch_bounds__(256) void gemm_mfma(
    const u16* __restrict__ A, const u16* __restrict__ Bt,
    const u16* __restrict__ bias, const void* __restrict__ res,
    void* __restrict__ outp,
    u16* __restrict__ qh, u16* __restrict__ kh, u16* __restrict__ vh,
    int N, int K)
{
    const int t = threadIdx.x;
    const int w = t >> 6, lane = t & 63;
    const int l15 = lane & 15, quad = lane >> 4;
    const int col0 = blockIdx.x * 64;
    const int row0 = blockIdx.y * 128;
    const int mrow = row0 + w * 32;

    const u16* Ap = A  + (size_t)(mrow + l15) * K + quad * 8;
    const u16* Bp = Bt + (size_t)(col0 + l15) * K + quad * 8;

    f4_t acc[2][4];
    #pragma unroll
    for (int mi = 0; mi < 2; ++mi)
        #pragma unroll
        for (int ni = 0; ni < 4; ++ni)
            acc[mi][ni] = (f4_t){0.f, 0.f, 0.f, 0.f};

    for (int k0 = 0; k0 < K; k0 += 64) {
        bf8_t a[2][2], bb[4][2];
        #pragma unroll
        for (int kc = 0; kc < 2; ++kc) {
            #pragma unroll
            for (int mi = 0; mi < 2; ++mi)
                a[mi][kc] = *(const bf8_t*)(Ap + (size_t)mi * 16 * K + k0 + kc * 32);
            #pragma unroll
            for (int ni = 0; ni < 4; ++ni)
                bb[ni][kc] = *(const bf8_t*)(Bp + (size_t)ni * 16 * K + k0 + kc * 32);
        }
        #pragma unroll
        for (int kc = 0; kc < 2; ++kc)
            #pragma unroll
            for (int ni = 0; ni < 4; ++ni)
                #pragma unroll
                for (int mi = 0; mi < 2; ++mi)
                    acc[mi][ni] = __builtin_amdgcn_mfma_f32_16x16x32_bf16(
                        a[mi][kc], bb[ni][kc], acc[mi][ni], 0, 0, 0);
    }

    if (MODE == EP_QKV) {
        if (col0 >= 512) {
            // V: transpose through LDS -> vhT[vchan][token] coalesced
            __shared__ u16 Ts[64][132];
            #pragma unroll
            for (int mi = 0; mi < 2; ++mi)
                #pragma unroll
                for (int ni = 0; ni < 4; ++ni) {
                    float bz = bf2f(bias[col0 + ni * 16 + l15]);
                    #pragma unroll
                    for (int r = 0; r < 4; ++r)
                        Ts[ni * 16 + l15][w * 32 + mi * 16 + quad * 4 + r] =
                            f2bf(acc[mi][ni][r] + bz);
                }
            __syncthreads();
            int vcg = col0 - 512;
            int hh  = vcg >> 8;
            int bb2 = row0 >> 11, nb = row0 & 2047;
            int cl  = t >> 2, seg = t & 3;
            u16* dp = vh + ((size_t)(bb2 * 8 + hh) * 256 + (vcg & 255) + cl) * 2048
                         + nb + seg * 32;
            #pragma unroll
            for (int ii = 0; ii < 32; ii += 4)
                *(ushort4*)(dp + ii) = *(const ushort4*)&Ts[cl][seg * 32 + ii];
        } else {
            #pragma unroll
            for (int mi = 0; mi < 2; ++mi)
                #pragma unroll
                for (int r = 0; r < 4; ++r) {
                    int rg = mrow + mi * 16 + quad * 4 + r;
                    int bb2 = rg >> 11, n = rg & 2047;
                    #pragma unroll
                    for (int ni = 0; ni < 4; ++ni) {
                        int col = col0 + ni * 16 + l15;
                        float v = acc[mi][ni][r] + bf2f(bias[col]);
                        if (col < 256)
                            qh[(((size_t)(bb2 * 8 + (col >> 5))) * 2048 + n) * 32 + (col & 31)] = f2bf(v);
                        else {
                            int c2 = col - 256;
                            kh[(((size_t)(bb2 * 8 + (c2 >> 5))) * 2048 + n) * 32 + (c2 & 31)] = f2bf(v);
                        }
                    }
                }
        }
    } else {
        float bz[4];
        #pragma unroll
        for (int ni = 0; ni < 4; ++ni) bz[ni] = bf2f(bias[col0 + ni * 16 + l15]);
        #pragma unroll
        for (int mi = 0; mi < 2; ++mi)
            #pragma unroll
            for (int r = 0; r < 4; ++r) {
                int rg = mrow + mi * 16 + quad * 4 + r;
                size_t base = (size_t)rg * N + col0 + l15;
                if (MODE == EP_MERGE) {          // + bm + x (bf16) -> f32 x2
                    const u16* R = (const u16*)res;
                    #pragma unroll
                    for (int ni = 0; ni < 4; ++ni)
                        ((float*)outp)[base + ni * 16] =
                            acc[mi][ni][r] + bz[ni] + bf2f(R[base + ni * 16]);
                } else if (MODE == EP_GELU) {    // exact gelu -> bf16 hidden
                    #pragma unroll
                    for (int ni = 0; ni < 4; ++ni) {
                        float v = acc[mi][ni][r] + bz[ni];
                        v = 0.5f * v * (1.0f + erff(v * 0.70710678118654752f));
                        ((u16*)outp)[base + ni * 16] = f2bf(v);
                    }
                } else {                          // EP_FFN2: + x2 (f32) -> fp32 d_out
                    const float* R = (const float*)res;
                    #pragma unroll
                    for (int ni = 0; ni < 4; ++ni)
                        ((float*)outp)[base + ni * 16] =
                            acc[mi][ni][r] + bz[ni] + R[base + ni * 16];
                }
            }
    }
}

// ---------------- MFMA flash attention (unchanged from R6-pass) ----------------
__global__ __launch_bounds__(256) void attn_k(
    const u16* __restrict__ qh, const u16* __restrict__ kh,
    const u16* __restrict__ vhT, u16* __restrict__ ao)
{
    const int t = threadIdx.x;
    const int w = t >> 6, lane = t & 63;
    const int l15 = lane & 15, quad = lane >> 4;
    const int qt = blockIdx.x, h = blockIdx.y, b = blockIdx.z;
    const int n0 = qt * 64;
    const float scale = 0.17677669529663687f;  // 1/sqrt(32)
    const size_t bh = (size_t)(b * 8 + h);
    const u16* Q  = qh  + bh * 2048 * 32;
    const u16* Kp = kh  + bh * 2048 * 32;
    const u16* Vt = vhT + bh * 256 * 2048;     // [vchan][key]

    __shared__ __align__(16) u16 Pb[64][72];
    __shared__ __align__(16) float alf[64];
    __shared__ __align__(16) float lds_l[64];
    __shared__ int flags[4];

    const bf8_t qf = *(const bf8_t*)(Q + (size_t)(n0 + 16 * w + l15) * 32 + quad * 8);

    f4_t acc[4][4];
    #pragma unroll
    for (int i = 0; i < 4; ++i)
        #pragma unroll
        for (int j = 0; j < 4; ++j)
            acc[i][j] = (f4_t){0.f, 0.f, 0.f, 0.f};
    float m4[4] = {-1e30f, -1e30f, -1e30f, -1e30f};
    float l4[4] = {0.f, 0.f, 0.f, 0.f};
    const f4_t zf = {0.f, 0.f, 0.f, 0.f};

    for (int kt = 0; kt < 2048; kt += 64) {
        f4_t s[4];
        #pragma unroll
        for (int jt = 0; jt < 4; ++jt) {
            bf8_t kf = *(const bf8_t*)(Kp + (size_t)(kt + jt * 16 + l15) * 32 + quad * 8);
            s[jt] = __builtin_amdgcn_mfma_f32_16x16x32_bf16(qf, kf, zf, 0, 0, 0);
        }
        float al[4];
        int any = 0;
        #pragma unroll
        for (int r = 0; r < 4; ++r) {
            float v0 = s[0][r] * scale, v1 = s[1][r] * scale;
            float v2 = s[2][r] * scale, v3 = s[3][r] * scale;
            float tm = fmaxf(fmaxf(v0, v1), fmaxf(v2, v3));
            #pragma unroll
            for (int d = 1; d < 16; d <<= 1) tm = fmaxf(tm, __shfl_xor(tm, d, 64));
            float mo = m4[r], mn = fmaxf(mo, tm);
            float a = __expf(mo - mn);
            float p0 = __expf(v0 - mn), p1 = __expf(v1 - mn);
            float p2 = __expf(v2 - mn), p3 = __expf(v3 - mn);
            float rsum = p0 + p1 + p2 + p3;
            #pragma unroll
            for (int d = 1; d < 16; d <<= 1) rsum += __shfl_xor(rsum, d, 64);
            m4[r] = mn; l4[r] = l4[r] * a + rsum; al[r] = a;
            any |= (a < 1.0f);
            int row = 16 * w + quad * 4 + r;
            Pb[row][l15]      = f2bf(p0);
            Pb[row][16 + l15] = f2bf(p1);
            Pb[row][32 + l15] = f2bf(p2);
            Pb[row][48 + l15] = f2bf(p3);
        }
        if (l15 == 0) {
            #pragma unroll
            for (int r = 0; r < 4; ++r) alf[16 * w + quad * 4 + r] = al[r];
        }
        unsigned long long bal = __ballot(any);
        if (lane == 0) flags[w] = (bal != 0ULL);
        __syncthreads();
        if (flags[0] | flags[1] | flags[2] | flags[3]) {
            #pragma unroll
            for (int mt = 0; mt < 4; ++mt) {
                f4_t a4 = *(const f4_t*)&alf[mt * 16 + quad * 4];
                #pragma unroll
                for (int nt = 0; nt < 4; ++nt)
                    #pragma unroll
                    for (int r = 0; r < 4; ++r)
                        acc[mt][nt][r] *= a4[r];
            }
        }
        #pragma unroll
        for (int kc = 0; kc < 2; ++kc) {
            bf8_t af[4];
            #pragma unroll
            for (int mt = 0; mt < 4; ++mt)
                af[mt] = *(const bf8_t*)&Pb[mt * 16 + l15][kc * 32 + quad * 8];
            #pragma unroll
            for (int nt = 0; nt < 4; ++nt) {
                bf8_t vf = *(const bf8_t*)(Vt + (size_t)(64 * w + nt * 16 + l15) * 2048
                                           + kt + kc * 32 + quad * 8);
                #pragma unroll
                for (int mt = 0; mt < 4; ++mt)
                    acc[mt][nt] = __builtin_amdgcn_mfma_f32_16x16x32_bf16(
                        af[mt], vf, acc[mt][nt], 0, 0, 0);
            }
        }
        __syncthreads();
    }

    if (l15 == 0) {
        #pragma unroll
        for (int r = 0; r < 4; ++r) lds_l[16 * w + quad * 4 + r] = l4[r];
    }
    __syncthreads();
    #pragma unroll
    for (int mt = 0; mt < 4; ++mt) {
        f4_t lv = *(const f4_t*)&lds_l[mt * 16 + quad * 4];
        #pragma unroll
        for (int r = 0; r < 4; ++r) {
            float inv = 1.0f / lv[r];
            size_t rowbase = ((size_t)(b * 2048 + n0 + mt * 16 + quad * 4 + r)) * 2048
                             + h * 256 + 64 * w;
            #pragma unroll
            for (int nt = 0; nt < 4; ++nt)
                ao[rowbase + nt * 16 + l15] = f2bf(acc[mt][nt][r] * inv);
        }
    }
}

extern "C" void kernel_launch(void* const* d_in, const int* in_sizes, int n_in,
                              void* d_out, int out_size, void* d_ws, size_t ws_size,
                              hipStream_t stream)
{
    u16* wsu = (u16*)d_ws;
    int* flag = (int*)d_ws;

    // workspace layout (u16 units), ~95.7 MB
    const size_t CVT0 = 64;
    const size_t Y0   = 3806272;                 // y bf16 [8192,256]
    const size_t QH0  = Y0  + 2097152;
    const size_t KH0  = QH0 + 2097152;
    const size_t VT0  = KH0 + 2097152;           // vhT bf16 [B*H*256][2048]
    const size_t AO0  = VT0 + 16777216;          // ao bf16 [8192][2048]
    const size_t X20  = AO0 + 16777216;          // x2 f32 [8192,256]
    // hbb bf16 [8192,1024] aliases ao (dead after merge GEMM)

    u16* cvt = wsu + CVT0;
    u16* y   = wsu + Y0;
    u16* qh  = wsu + QH0;
    u16* kh  = wsu + KH0;
    u16* vhT = wsu + VT0;
    u16* ao  = wsu + AO0;
    float* x2 = (float*)(wsu + X20);
    u16* hbb  = wsu + AO0;

    const u16* xc   = cvt + SEG_X;
    const u16* ln1g = cvt + SEG_LN1G;
    const u16* ln1b = cvt + SEG_LN1B;
    const u16* Wqkv = cvt + SEG_WQKV;   // transposed [2560][256]
    const u16* bqkv = cvt + SEG_BQKV;
    const u16* Wm   = cvt + SEG_WM;     // transposed [256][2048]
    const u16* bm   = cvt + SEG_BM;
    const u16* ln2g = cvt + SEG_LN2G;
    const u16* ln2b = cvt + SEG_LN2B;
    const u16* W1   = cvt + SEG_W1;     // transposed [1024][256]
    const u16* b1   = cvt + SEG_B1;
    const u16* W2   = cvt + SEG_W2;     // transposed [256][1024]
    const u16* b2   = cvt + SEG_B2;

    sniff_k<<<1, 256, 0, stream>>>((const u16*)d_in[0], flag);
    conv_k<<<SEG_TOT / 256, 256, 0, stream>>>(
        d_in[0], d_in[1], d_in[2], d_in[3], d_in[4], d_in[5], d_in[6],
        d_in[7], d_in[8], d_in[9], d_in[10], d_in[11], d_in[12], flag, cvt);

    ln_k<true><<<ROWS, 256, 0, stream>>>(xc, ln1g, ln1b, y);
    gemm_mfma<EP_QKV><<<dim3(2560 / 64, ROWS / 128), 256, 0, stream>>>(
        y, Wqkv, bqkv, nullptr, nullptr, qh, kh, vhT, 2560, 256);
    attn_k<<<dim3(32, H_, B_), 256, 0, stream>>>(qh, kh, vhT, ao);
    gemm_mfma<EP_MERGE><<<dim3(256 / 64, ROWS / 128), 256, 0, stream>>>(
        ao, Wm, bm, xc, x2, nullptr, nullptr, nullptr, 256, 2048);
    ln_k<false><<<ROWS, 256, 0, stream>>>(x2, ln2g, ln2b, y);
    gemm_mfma<EP_GELU><<<dim3(1024 / 64, ROWS / 128), 256, 0, stream>>>(
        y, W1, b1, nullptr, hbb, nullptr, nullptr, nullptr, 1024, 256);
    gemm_mfma<EP_FFN2><<<dim3(256 / 64, ROWS / 128), 256, 0, stream>>>(
        hbb, W2, b2, x2, d_out, nullptr, nullptr, nullptr, 256, 1024);
}

// Round 8
// 483.062 us; speedup vs baseline: 5.3695x; 1.0383x over previous
//
#include <hip/hip_runtime.h>

typedef unsigned short u16;
typedef __attribute__((ext_vector_type(8))) short bf8_t;   // 8 bf16 (4 VGPR) MFMA A/B frag
typedef __attribute__((ext_vector_type(4))) float f4_t;    // MFMA C/D frag

__device__ __forceinline__ float bf2f(u16 v) {
    union { unsigned u; float f; } c; c.u = ((unsigned)v) << 16; return c.f;
}
__device__ __forceinline__ u16 f2bf(float f) {  // RNE f32 -> bf16
    union { float f; unsigned u; } c; c.f = f;
    unsigned r = 0x7FFFu + ((c.u >> 16) & 1u);
    return (u16)((c.u + r) >> 16);
}

#define B_   4
#define N_   2048
#define INC  256
#define H_   8
#define ROWS 8192

// canonical (bf16) segment offsets within cvt, u16 units. Weights stored TRANSPOSED: Bt[n][k].
#define SEG_X     0
#define SEG_LN1G  2097152
#define SEG_LN1B  2097408
#define SEG_WQKV  2097664
#define SEG_BQKV  2753024
#define SEG_WM    2755584
#define SEG_BM    3279872
#define SEG_LN2G  3280128
#define SEG_LN2B  3280384
#define SEG_W1    3280640
#define SEG_B1    3542784
#define SEG_W2    3543808
#define SEG_B2    3805952
#define SEG_TOT   3806208

// ---------------- dtype sniffer ----------------
__global__ __launch_bounds__(256) void sniff_k(const u16* __restrict__ x, int* __restrict__ flag) {
    __shared__ int s;
    int t = threadIdx.x;
    if (t == 0) s = 0;
    __syncthreads();
    int bad = 0;
    for (int i = t; i < 8192; i += 256) {
        float v = bf2f(x[i]);
        if (!(fabsf(v) < 1e10f)) bad = 1;
    }
    if (bad) atomicOr(&s, 1);
    __syncthreads();
    if (t == 0) *flag = s;   // 1 => inputs fp32, 0 => bf16
}

// ---------------- canonicalize inputs to bf16; weights transposed ----------------
__global__ __launch_bounds__(256) void conv_k(
    const void* p0, const void* p1, const void* p2, const void* p3, const void* p4,
    const void* p5, const void* p6, const void* p7, const void* p8, const void* p9,
    const void* p10, const void* p11, const void* p12,
    const int* __restrict__ flag, u16* __restrict__ dst)
{
    int i = blockIdx.x * 256 + threadIdx.x;
    if (i >= SEG_TOT) return;
    const void* p; int j;
    if      (i < SEG_LN1G) { p = p0;  j = i; }
    else if (i < SEG_LN1B) { p = p1;  j = i - SEG_LN1G; }
    else if (i < SEG_WQKV) { p = p2;  j = i - SEG_LN1B; }
    else if (i < SEG_BQKV) { p = p3;  int ii = i - SEG_WQKV;          // WqkvT[n][k]: n<2560,k<256
                             int n = ii >> 8, k = ii & 255; j = k * 2560 + n; }
    else if (i < SEG_WM)   { p = p4;  j = i - SEG_BQKV; }
    else if (i < SEG_BM)   { p = p5;  int ii = i - SEG_WM;            // WmT[n][k]: n<256,k<2048
                             int n = ii >> 11, k = ii & 2047; j = k * 256 + n; }
    else if (i < SEG_LN2G) { p = p6;  j = i - SEG_BM; }
    else if (i < SEG_LN2B) { p = p7;  j = i - SEG_LN2G; }
    else if (i < SEG_W1)   { p = p8;  j = i - SEG_LN2B; }
    else if (i < SEG_B1)   { p = p9;  int ii = i - SEG_W1;            // W1T[n][k]: n<1024,k<256
                             int n = ii >> 8, k = ii & 255; j = k * 1024 + n; }
    else if (i < SEG_W2)   { p = p10; j = i - SEG_B1; }
    else if (i < SEG_B2)   { p = p11; int ii = i - SEG_W2;            // W2T[n][k]: n<256,k<1024
                             int n = ii >> 10, k = ii & 1023; j = k * 256 + n; }
    else                   { p = p12; j = i - SEG_B2; }
    dst[i] = (*flag) ? f2bf(((const float*)p)[j]) : ((const u16*)p)[j];
}

// ---------------- LayerNorm over C=256, one block per row, bf16 out ----------------
template<bool BF16IN>
__global__ __launch_bounds__(256) void ln_k(const void* __restrict__ xp,
        const u16* __restrict__ g, const u16* __restrict__ b, u16* __restrict__ y)
{
    int row = blockIdx.x, t = threadIdx.x;
    float v;
    if (BF16IN) v = bf2f(((const u16*)xp)[(size_t)row * INC + t]);
    else        v = ((const float*)xp)[(size_t)row * INC + t];
    float s = v, s2 = v * v;
    #pragma unroll
    for (int o = 32; o > 0; o >>= 1) {
        s  += __shfl_down(s,  o, 64);
        s2 += __shfl_down(s2, o, 64);
    }
    __shared__ float rs[4], rq[4];
    if ((t & 63) == 0) { rs[t >> 6] = s; rq[t >> 6] = s2; }
    __syncthreads();
    float S  = rs[0] + rs[1] + rs[2] + rs[3];
    float S2 = rq[0] + rq[1] + rq[2] + rq[3];
    float mean = S * (1.0f / INC);
    float var  = S2 * (1.0f / INC) - mean * mean;
    float inv  = rsqrtf(var + 1e-5f);
    y[(size_t)row * INC + t] = f2bf((v - mean) * inv * bf2f(g[t]) + bf2f(b[t]));
}

// ---------------- MFMA GEMM: C[M,N] = A[M,K](bf16) @ Bt[N,K]^T + epilogue ----------------
enum { EP_QKV = 0, EP_MERGE = 1, EP_GELU = 2, EP_FFN2 = 3 };

template<int MODE>
__global__ __launch_bounds__(256) void gemm_mfma(
    const u16* __restrict__ A, const u16* __restrict__ Bt,
    const u16* __restrict__ bias, const void* __restrict__ res,
    void* __restrict__ outp,
    u16* __restrict__ qh, u16* __restrict__ kh, u16* __restrict__ vh,
    int N, int K)
{
    const int t = threadIdx.x;
    const int w = t >> 6, lane = t & 63;
    const int l15 = lane & 15, quad = lane >> 4;
    const int col0 = blockIdx.x * 64;
    const int row0 = blockIdx.y * 128;
    const int mrow = row0 + w * 32;

    const u16* Ap = A  + (size_t)(mrow + l15) * K + quad * 8;
    const u16* Bp = Bt + (size_t)(col0 + l15) * K + quad * 8;

    f4_t acc[2][4];
    #pragma unroll
    for (int mi = 0; mi < 2; ++mi)
        #pragma unroll
        for (int ni = 0; ni < 4; ++ni)
            acc[mi][ni] = (f4_t){0.f, 0.f, 0.f, 0.f};

    for (int k0 = 0; k0 < K; k0 += 64) {
        bf8_t a[2][2], bb[4][2];
        #pragma unroll
        for (int kc = 0; kc < 2; ++kc) {
            #pragma unroll
            for (int mi = 0; mi < 2; ++mi)
                a[mi][kc] = *(const bf8_t*)(Ap + (size_t)mi * 16 * K + k0 + kc * 32);
            #pragma unroll
            for (int ni = 0; ni < 4; ++ni)
                bb[ni][kc] = *(const bf8_t*)(Bp + (size_t)ni * 16 * K + k0 + kc * 32);
        }
        #pragma unroll
        for (int kc = 0; kc < 2; ++kc)
            #pragma unroll
            for (int ni = 0; ni < 4; ++ni)
                #pragma unroll
                for (int mi = 0; mi < 2; ++mi)
                    acc[mi][ni] = __builtin_amdgcn_mfma_f32_16x16x32_bf16(
                        a[mi][kc], bb[ni][kc], acc[mi][ni], 0, 0, 0);
    }

    if (MODE == EP_QKV) {
        if (col0 >= 512) {
            // V: transpose through LDS -> vhT[vchan][token] coalesced
            __shared__ u16 Ts[64][132];
            #pragma unroll
            for (int mi = 0; mi < 2; ++mi)
                #pragma unroll
                for (int ni = 0; ni < 4; ++ni) {
                    float bz = bf2f(bias[col0 + ni * 16 + l15]);
                    #pragma unroll
                    for (int r = 0; r < 4; ++r)
                        Ts[ni * 16 + l15][w * 32 + mi * 16 + quad * 4 + r] =
                            f2bf(acc[mi][ni][r] + bz);
                }
            __syncthreads();
            int vcg = col0 - 512;
            int hh  = vcg >> 8;
            int bb2 = row0 >> 11, nb = row0 & 2047;
            int cl  = t >> 2, seg = t & 3;
            u16* dp = vh + ((size_t)(bb2 * 8 + hh) * 256 + (vcg & 255) + cl) * 2048
                         + nb + seg * 32;
            #pragma unroll
            for (int ii = 0; ii < 32; ii += 4)
                *(ushort4*)(dp + ii) = *(const ushort4*)&Ts[cl][seg * 32 + ii];
        } else {
            #pragma unroll
            for (int mi = 0; mi < 2; ++mi)
                #pragma unroll
                for (int r = 0; r < 4; ++r) {
                    int rg = mrow + mi * 16 + quad * 4 + r;
                    int bb2 = rg >> 11, n = rg & 2047;
                    #pragma unroll
                    for (int ni = 0; ni < 4; ++ni) {
                        int col = col0 + ni * 16 + l15;
                        float v = acc[mi][ni][r] + bf2f(bias[col]);
                        if (col < 256)
                            qh[(((size_t)(bb2 * 8 + (col >> 5))) * 2048 + n) * 32 + (col & 31)] = f2bf(v);
                        else {
                            int c2 = col - 256;
                            kh[(((size_t)(bb2 * 8 + (c2 >> 5))) * 2048 + n) * 32 + (c2 & 31)] = f2bf(v);
                        }
                    }
                }
        }
    } else {
        float bz[4];
        #pragma unroll
        for (int ni = 0; ni < 4; ++ni) bz[ni] = bf2f(bias[col0 + ni * 16 + l15]);
        #pragma unroll
        for (int mi = 0; mi < 2; ++mi)
            #pragma unroll
            for (int r = 0; r < 4; ++r) {
                int rg = mrow + mi * 16 + quad * 4 + r;
                size_t base = (size_t)rg * N + col0 + l15;
                if (MODE == EP_MERGE) {          // + bm + x (bf16) -> f32 x2
                    const u16* R = (const u16*)res;
                    #pragma unroll
                    for (int ni = 0; ni < 4; ++ni)
                        ((float*)outp)[base + ni * 16] =
                            acc[mi][ni][r] + bz[ni] + bf2f(R[base + ni * 16]);
                } else if (MODE == EP_GELU) {    // exact gelu -> bf16 hidden
                    #pragma unroll
                    for (int ni = 0; ni < 4; ++ni) {
                        float v = acc[mi][ni][r] + bz[ni];
                        v = 0.5f * v * (1.0f + erff(v * 0.70710678118654752f));
                        ((u16*)outp)[base + ni * 16] = f2bf(v);
                    }
                } else {                          // EP_FFN2: + x2 (f32) -> fp32 d_out
                    const float* R = (const float*)res;
                    #pragma unroll
                    for (int ni = 0; ni < 4; ++ni)
                        ((float*)outp)[base + ni * 16] =
                            acc[mi][ni][r] + bz[ni] + R[base + ni * 16];
                }
            }
    }
}

// ---------------- MFMA flash attention, two-pass softmax ----------------
// 1D grid, 1024 blocks, XCD-swizzled: id = g*256 + qt*8 + (bh&7) so all q-tiles
// of one (b,h) share id%8 (same XCD) -> K/V head L2-resident.
// Block: 64 q rows, 4 waves. Wave w: softmax rows 16w..16w+15, O cols 64w..64w+63.
__global__ __launch_bounds__(256) void attn_k(
    const u16* __restrict__ qh, const u16* __restrict__ kh,
    const u16* __restrict__ vhT, u16* __restrict__ ao)
{
    const int t = threadIdx.x;
    const int w = t >> 6, lane = t & 63;
    const int l15 = lane & 15, quad = lane >> 4;
    const int id = blockIdx.x;
    const int qt = (id >> 3) & 31;
    const int bh = (id >> 8) * 8 + (id & 7);
    const int b  = bh >> 3, h = bh & 7;
    const int n0 = qt * 64;
    const float scale = 0.17677669529663687f;  // 1/sqrt(32)

    const u16* Q  = qh  + (size_t)bh * 2048 * 32;
    const u16* Kp = kh  + (size_t)bh * 2048 * 32;
    const u16* Vt = vhT + (size_t)bh * 256 * 2048;   // [vchan][key]

    __shared__ __align__(16) u16 Pb[2][64][72];
    __shared__ __align__(16) float lds_l[64];

    const bf8_t qf = *(const bf8_t*)(Q + (size_t)(n0 + 16 * w + l15) * 32 + quad * 8);
    const f4_t zf = {0.f, 0.f, 0.f, 0.f};

    // ---- pass A: global row max (barrier-free, LDS-free) ----
    float m4[4] = {-1e30f, -1e30f, -1e30f, -1e30f};
    for (int kt = 0; kt < 2048; kt += 64) {
        #pragma unroll
        for (int jt = 0; jt < 4; ++jt) {
            bf8_t kf = *(const bf8_t*)(Kp + (size_t)(kt + jt * 16 + l15) * 32 + quad * 8);
            f4_t s = __builtin_amdgcn_mfma_f32_16x16x32_bf16(qf, kf, zf, 0, 0, 0);
            #pragma unroll
            for (int r = 0; r < 4; ++r) m4[r] = fmaxf(m4[r], s[r]);
        }
    }
    #pragma unroll
    for (int r = 0; r < 4; ++r) {
        #pragma unroll
        for (int d = 1; d < 16; d <<= 1)
            m4[r] = fmaxf(m4[r], __shfl_xor(m4[r], d, 64));
        m4[r] *= scale;   // fixed max, scaled domain
    }

    // ---- pass B: P = exp(s*scale - m), O += P V ----
    f4_t acc[4][4];
    #pragma unroll
    for (int i = 0; i < 4; ++i)
        #pragma unroll
        for (int j = 0; j < 4; ++j)
            acc[i][j] = (f4_t){0.f, 0.f, 0.f, 0.f};
    float l4[4] = {0.f, 0.f, 0.f, 0.f};

    int bufi = 0;
    for (int kt = 0; kt < 2048; kt += 64, bufi ^= 1) {
        #pragma unroll
        for (int jt = 0; jt < 4; ++jt) {
            bf8_t kf = *(const bf8_t*)(Kp + (size_t)(kt + jt * 16 + l15) * 32 + quad * 8);
            f4_t s = __builtin_amdgcn_mfma_f32_16x16x32_bf16(qf, kf, zf, 0, 0, 0);
            #pragma unroll
            for (int r = 0; r < 4; ++r) {
                float p = __expf(fmaf(s[r], scale, -m4[r]));
                l4[r] += p;
                Pb[bufi][16 * w + quad * 4 + r][jt * 16 + l15] = f2bf(p);
            }
        }
        __syncthreads();   // Pb[bufi] complete; prev buffer reads already done
        #pragma unroll
        for (int kc = 0; kc < 2; ++kc) {
            bf8_t af[4];
            #pragma unroll
            for (int mt = 0; mt < 4; ++mt)
                af[mt] = *(const bf8_t*)&Pb[bufi][mt * 16 + l15][kc * 32 + quad * 8];
            #pragma unroll
            for (int nt = 0; nt < 4; ++nt) {
                bf8_t vf = *(const bf8_t*)(Vt + (size_t)(64 * w + nt * 16 + l15) * 2048
                                           + kt + kc * 32 + quad * 8);
                #pragma unroll
                for (int mt = 0; mt < 4; ++mt)
                    acc[mt][nt] = __builtin_amdgcn_mfma_f32_16x16x32_bf16(
                        af[mt], vf, acc[mt][nt], 0, 0, 0);
            }
        }
    }

    // ---- l reduce (once) and epilogue ----
    #pragma unroll
    for (int r = 0; r < 4; ++r) {
        #pragma unroll
        for (int d = 1; d < 16; d <<= 1) l4[r] += __shfl_xor(l4[r], d, 64);
    }
    if (l15 == 0) {
        #pragma unroll
        for (int r = 0; r < 4; ++r) lds_l[16 * w + quad * 4 + r] = l4[r];
    }
    __syncthreads();
    #pragma unroll
    for (int mt = 0; mt < 4; ++mt) {
        f4_t lv = *(const f4_t*)&lds_l[mt * 16 + quad * 4];
        #pragma unroll
        for (int r = 0; r < 4; ++r) {
            float inv = 1.0f / lv[r];
            size_t rowbase = ((size_t)(b * 2048 + n0 + mt * 16 + quad * 4 + r)) * 2048
                             + h * 256 + 64 * w;
            #pragma unroll
            for (int nt = 0; nt < 4; ++nt)
                ao[rowbase + nt * 16 + l15] = f2bf(acc[mt][nt][r] * inv);
        }
    }
}

extern "C" void kernel_launch(void* const* d_in, const int* in_sizes, int n_in,
                              void* d_out, int out_size, void* d_ws, size_t ws_size,
                              hipStream_t stream)
{
    u16* wsu = (u16*)d_ws;
    int* flag = (int*)d_ws;

    // workspace layout (u16 units), ~95.7 MB
    const size_t CVT0 = 64;
    const size_t Y0   = 3806272;                 // y bf16 [8192,256]
    const size_t QH0  = Y0  + 2097152;
    const size_t KH0  = QH0 + 2097152;
    const size_t VT0  = KH0 + 2097152;           // vhT bf16 [B*H*256][2048]
    const size_t AO0  = VT0 + 16777216;          // ao bf16 [8192][2048]
    const size_t X20  = AO0 + 16777216;          // x2 f32 [8192,256]
    // hbb bf16 [8192,1024] aliases ao (dead after merge GEMM)

    u16* cvt = wsu + CVT0;
    u16* y   = wsu + Y0;
    u16* qh  = wsu + QH0;
    u16* kh  = wsu + KH0;
    u16* vhT = wsu + VT0;
    u16* ao  = wsu + AO0;
    float* x2 = (float*)(wsu + X20);
    u16* hbb  = wsu + AO0;

    const u16* xc   = cvt + SEG_X;
    const u16* ln1g = cvt + SEG_LN1G;
    const u16* ln1b = cvt + SEG_LN1B;
    const u16* Wqkv = cvt + SEG_WQKV;   // transposed [2560][256]
    const u16* bqkv = cvt + SEG_BQKV;
    const u16* Wm   = cvt + SEG_WM;     // transposed [256][2048]
    const u16* bm   = cvt + SEG_BM;
    const u16* ln2g = cvt + SEG_LN2G;
    const u16* ln2b = cvt + SEG_LN2B;
    const u16* W1   = cvt + SEG_W1;     // transposed [1024][256]
    const u16* b1   = cvt + SEG_B1;
    const u16* W2   = cvt + SEG_W2;     // transposed [256][1024]
    const u16* b2   = cvt + SEG_B2;

    sniff_k<<<1, 256, 0, stream>>>((const u16*)d_in[0], flag);
    conv_k<<<SEG_TOT / 256, 256, 0, stream>>>(
        d_in[0], d_in[1], d_in[2], d_in[3], d_in[4], d_in[5], d_in[6],
        d_in[7], d_in[8], d_in[9], d_in[10], d_in[11], d_in[12], flag, cvt);

    ln_k<true><<<ROWS, 256, 0, stream>>>(xc, ln1g, ln1b, y);
    gemm_mfma<EP_QKV><<<dim3(2560 / 64, ROWS / 128), 256, 0, stream>>>(
        y, Wqkv, bqkv, nullptr, nullptr, qh, kh, vhT, 2560, 256);
    attn_k<<<1024, 256, 0, stream>>>(qh, kh, vhT, ao);
    gemm_mfma<EP_MERGE><<<dim3(256 / 64, ROWS / 128), 256, 0, stream>>>(
        ao, Wm, bm, xc, x2, nullptr, nullptr, nullptr, 256, 2048);
    ln_k<false><<<ROWS, 256, 0, stream>>>(x2, ln2g, ln2b, y);
    gemm_mfma<EP_GELU><<<dim3(1024 / 64, ROWS / 128), 256, 0, stream>>>(
        y, W1, b1, nullptr, hbb, nullptr, nullptr, nullptr, 1024, 256);
    gemm_mfma<EP_FFN2><<<dim3(256 / 64, ROWS / 128), 256, 0, stream>>>(
        hbb, W2, b2, x2, d_out, nullptr, nullptr, nullptr, 256, 1024);
}